// Round 9
// baseline (252.644 us; speedup 1.0000x reference)
//
#include <hip/hip_runtime.h>
#include <math.h>

typedef short  short8  __attribute__((ext_vector_type(8)));
typedef short  short4v __attribute__((ext_vector_type(4)));
typedef float  f32x4   __attribute__((ext_vector_type(4)));

constexpr int D   = 1024;   // d_in = d_g
constexpr int K   = 512;    // codebook size
constexpr int BM  = 128;    // rows per block (vq_topk)
constexpr int KP  = 256;    // k-panel (f32 elements)
constexpr int ROWS = 16384;
constexpr float GAP_T = 2e-3f;   // ~400 sigma of 3-term split-bf16 noise

__device__ __forceinline__ unsigned short f2bf(float f) {
    unsigned u = __float_as_uint(f);
    u += 0x7FFFu + ((u >> 16) & 1u);          // round-to-nearest-even
    return (unsigned short)(u >> 16);
}
__device__ __forceinline__ float bf2f(unsigned short h) {
    return __uint_as_float(((unsigned)h) << 16);
}

// ---------------------------------------------------------------------------
// Kernel A: normalize codebook rows; emit MFMA-fragment-packed bf16 hi/lo
// (cbp) + f32 copy (cff, for rescue). Also zeroes the rescue counter.
// Fragment fi = (code_tile*32 + kstep)*2 + h: 64 lanes x 16B; lane (lg,lr)
// holds codes[tile*16+lr][kstep*32 + lg*8 .. +8].
// ---------------------------------------------------------------------------
__global__ __launch_bounds__(256)
void prep_codebook(const float* __restrict__ cb, unsigned short* __restrict__ cbp,
                   float* __restrict__ cff, int* __restrict__ rcnt) {
    if (blockIdx.x == 0 && threadIdx.x == 0) rcnt[0] = 0;
    const int n = blockIdx.x, tid = threadIdx.x;
    const float4 v = reinterpret_cast<const float4*>(cb + (size_t)n * D)[tid];
    float ss = v.x*v.x + v.y*v.y + v.z*v.z + v.w*v.w;
#pragma unroll
    for (int off = 32; off > 0; off >>= 1) ss += __shfl_down(ss, off);
    __shared__ float wss[4];
    if ((tid & 63) == 0) wss[tid >> 6] = ss;
    __syncthreads();
    const float tot   = wss[0] + wss[1] + wss[2] + wss[3];
    const float scale = 1.0f / fmaxf(sqrtf(tot), 1e-12f);
    float f[4] = { v.x*scale, v.y*scale, v.z*scale, v.w*scale };
    float4 fv = { f[0], f[1], f[2], f[3] };
    reinterpret_cast<float4*>(cff + (size_t)n * D)[tid] = fv;

    unsigned short h[4], lo[4];
#pragma unroll
    for (int i = 0; i < 4; ++i) { h[i] = f2bf(f[i]); lo[i] = f2bf(f[i] - bf2f(h[i])); }
    short4v hv = { (short)h[0], (short)h[1], (short)h[2], (short)h[3] };
    short4v lv = { (short)lo[0], (short)lo[1], (short)lo[2], (short)lo[3] };

    const int nt_g = n >> 4;           // code tile 0..31
    const int lr   = n & 15;
    const int ks_g = tid >> 3;         // k-step 0..31
    const int lg   = (tid >> 1) & 3;
    const int half = tid & 1;
    const size_t fbase = ((size_t)(nt_g * 32 + ks_g) * 2) * 1024;   // bytes
    unsigned char* base = (unsigned char*)cbp;
    *reinterpret_cast<short4v*>(base + fbase + (lg * 16 + lr) * 16 + half * 8) = hv;
    *reinterpret_cast<short4v*>(base + fbase + 1024 + (lg * 16 + lr) * 16 + half * 8) = lv;
}

// ---------------------------------------------------------------------------
// Kernel B: 3-product split-bf16 MFMA GEMM, 128 rows x 256 codes per block.
// grid 256 = (half = bid>>7) x (rowblk = bid&127): both halves of one row
// panel land on the same XCD (bid%8) for z L2 reuse. 8 waves; wave wv owns
// codes half*256 + wv*32 .. +32 (nt=2). Per k-step: 48 MFMA vs 4 B-loads.
// Writes per-half top-2 (v1,v2,i1) to workspace; merged by vq_merge.
// ---------------------------------------------------------------------------
__global__ __launch_bounds__(512, 2)
void vq_topk(const float* __restrict__ z,
             const unsigned short* __restrict__ cbp,
             float* __restrict__ hv1, float* __restrict__ hv2,
             int* __restrict__ hi1) {
    __shared__ alignas(16) unsigned char AhB[BM * KP * 2];   // 64 KB swizzled hi
    __shared__ alignas(16) unsigned char AlB[BM * KP * 2];   // 64 KB swizzled lo

    const int tid  = threadIdx.x;
    const int half = blockIdx.x >> 7;     // 0..1 (code half)
    const int rblk = blockIdx.x & 127;    // 0..127 (row panel)
    const int r0   = rblk * BM;
    const int l    = tid & 63;
    const int wv   = tid >> 6;            // 0..7
    const int lr   = l & 15;
    const int lg   = l >> 4;

    f32x4 acc[8][2];
#pragma unroll
    for (int m = 0; m < 8; ++m)
#pragma unroll
        for (int nt = 0; nt < 2; ++nt) acc[m][nt] = (f32x4){0.f, 0.f, 0.f, 0.f};

    const int aswz = (lr & 7) << 4;
    const short8* bp = reinterpret_cast<const short8*>(cbp) + l;

    // staging decomposition: thread covers rows row0+8c (c=0..15) at f4-col c4
    const int c4    = tid & 63;
    const int row0  = tid >> 6;           // 0..7
    const int swz_w = (row0 & 7) << 4;    // (row0+8c)&7 == row0&7
    const float* zbase = z + (size_t)(r0 + row0) * D + c4 * 4;

    // prologue: load + convert panel 0
    short4v hreg[16], lreg[16];
#pragma unroll
    for (int c = 0; c < 16; ++c) {
        const float4 v = *reinterpret_cast<const float4*>(zbase + (size_t)(8 * c) * D);
        unsigned short h0 = f2bf(v.x), h1 = f2bf(v.y), h2 = f2bf(v.z), h3 = f2bf(v.w);
        hreg[c] = (short4v){ (short)h0, (short)h1, (short)h2, (short)h3 };
        lreg[c] = (short4v){ (short)f2bf(v.x - bf2f(h0)), (short)f2bf(v.y - bf2f(h1)),
                             (short)f2bf(v.z - bf2f(h2)), (short)f2bf(v.w - bf2f(h3)) };
    }

    for (int p = 0; p < 4; ++p) {
        if (p) __syncthreads();
        // ---- write converted panel -> swizzled LDS ----
#pragma unroll
        for (int c = 0; c < 16; ++c) {
            const int ad = ((row0 + 8 * c) * 512 + c4 * 8) ^ swz_w;
            *reinterpret_cast<short4v*>(AhB + ad) = hreg[c];
            *reinterpret_cast<short4v*>(AlB + ad) = lreg[c];
        }
        __syncthreads();
        // ---- issue next panel's global loads (consumed after MFMA loop) ----
        float4 znext[16];
        if (p < 3) {
#pragma unroll
            for (int c = 0; c < 16; ++c)
                znext[c] = *reinterpret_cast<const float4*>(
                    zbase + (size_t)(8 * c) * D + (p + 1) * KP);
        }
        // ---- MFMA: 8 k-steps of 32; B reg-dbuf (4 loads per step) ----
        short8 bb[2][2][2];
#pragma unroll
        for (int nt = 0; nt < 2; ++nt) {
            const size_t fi = ((size_t)((half * 16 + wv * 2 + nt) * 32 + p * 8) * 2);
            bb[0][nt][0] = bp[(fi + 0) * 64];
            bb[0][nt][1] = bp[(fi + 1) * 64];
        }
#pragma unroll
        for (int ks = 0; ks < 8; ++ks) {
            const int cur = ks & 1, nxt = cur ^ 1;
            if (ks < 7) {
#pragma unroll
                for (int nt = 0; nt < 2; ++nt) {
                    const size_t fi = ((size_t)((half * 16 + wv * 2 + nt) * 32 + p * 8 + ks + 1) * 2);
                    bb[nxt][nt][0] = bp[(fi + 0) * 64];
                    bb[nxt][nt][1] = bp[(fi + 1) * 64];
                }
            }
#pragma unroll
            for (int m = 0; m < 8; ++m) {
                const int ad = ((m * 16 + lr) * 512 + lg * 16 + ks * 64) ^ aswz;
                const short8 ah = *reinterpret_cast<const short8*>(AhB + ad);
                const short8 al = *reinterpret_cast<const short8*>(AlB + ad);
#pragma unroll
                for (int nt = 0; nt < 2; ++nt) {
                    acc[m][nt] = __builtin_amdgcn_mfma_f32_16x16x32_bf16(ah, bb[cur][nt][0], acc[m][nt], 0, 0, 0);
                    acc[m][nt] = __builtin_amdgcn_mfma_f32_16x16x32_bf16(ah, bb[cur][nt][1], acc[m][nt], 0, 0, 0);
                    acc[m][nt] = __builtin_amdgcn_mfma_f32_16x16x32_bf16(al, bb[cur][nt][0], acc[m][nt], 0, 0, 0);
                }
            }
        }
        // ---- convert next panel (VALU; overlaps/trails matrix pipe) ----
        if (p < 3) {
#pragma unroll
            for (int c = 0; c < 16; ++c) {
                const float4 v = znext[c];
                unsigned short h0 = f2bf(v.x), h1 = f2bf(v.y), h2 = f2bf(v.z), h3 = f2bf(v.w);
                hreg[c] = (short4v){ (short)h0, (short)h1, (short)h2, (short)h3 };
                lreg[c] = (short4v){ (short)f2bf(v.x - bf2f(h0)), (short)f2bf(v.y - bf2f(h1)),
                                     (short)f2bf(v.z - bf2f(h2)), (short)f2bf(v.w - bf2f(h3)) };
            }
        }
    }

    // ---- LDS no longer needed for A: alias reduction arrays onto AhB ----
    __syncthreads();
    float* cv1 = (float*)AhB;                 // [8][BM]
    float* cv2 = (float*)(AhB + 4096);        // [8][BM]
    int*   ci1 = (int*)  (AhB + 8192);        // [8][BM]

    // ---- top-2 per row: nt scan, 16-lane butterfly ----
    // acc[m][nt][r] = logits[row = m*16 + lg*4 + r][code = half*256 + wv*32 + nt*16 + lr]
#pragma unroll
    for (int m = 0; m < 8; ++m)
#pragma unroll
        for (int r = 0; r < 4; ++r) {
            float v1 = acc[m][0][r];
            int   i1 = half * 256 + wv * 32 + lr;
            float v2 = -INFINITY;
            {
                const float v = acc[m][1][r];
                const int   n = half * 256 + wv * 32 + 16 + lr;
                if (v > v1) { v2 = v1; v1 = v; i1 = n; }
                else        { v2 = v; }
            }
#pragma unroll
            for (int msk = 1; msk < 16; msk <<= 1) {
                const float ov1 = __shfl_xor(v1, msk);
                const float ov2 = __shfl_xor(v2, msk);
                const int   oi1 = __shfl_xor(i1, msk);
                if (ov1 > v1 || (ov1 == v1 && oi1 < i1)) { v2 = fmaxf(v1, ov2); v1 = ov1; i1 = oi1; }
                else                                     { v2 = fmaxf(v2, ov1); }
            }
            if (lr == 0) {
                const int row = m * 16 + lg * 4 + r;
                cv1[wv * BM + row] = v1; cv2[wv * BM + row] = v2; ci1[wv * BM + row] = i1;
            }
        }
    __syncthreads();
    // ---- cross-wave merge (rows 0..127), write per-half triple ----
    if (tid < BM) {
        float v1 = cv1[tid], v2 = cv2[tid];
        int   i1 = ci1[tid];
        for (int w = 1; w < 8; ++w) {
            const float a1 = cv1[w * BM + tid], a2 = cv2[w * BM + tid];
            const int   b1 = ci1[w * BM + tid];
            if (a1 > v1 || (a1 == v1 && b1 < i1)) { v2 = fmaxf(v1, a2); v1 = a1; i1 = b1; }
            else                                  { v2 = fmaxf(v2, a1); }
        }
        const size_t g = (size_t)(r0 + tid) * 2 + half;
        hv1[g] = v1; hv2[g] = v2; hi1[g] = i1;
    }
}

// ---------------------------------------------------------------------------
// Kernel C: merge the two code-halves' top-2 -> bestk + rescue list.
// Half-0 indices are always < half-1 indices, so ties pick half 0.
// ---------------------------------------------------------------------------
__global__ __launch_bounds__(256)
void vq_merge(const float* __restrict__ hv1, const float* __restrict__ hv2,
              const int* __restrict__ hi1, int* __restrict__ bestk,
              int* __restrict__ rlist, int* __restrict__ rcnt) {
    const int row = blockIdx.x * 256 + threadIdx.x;
    const float v1a = hv1[(size_t)row * 2],     v1b = hv1[(size_t)row * 2 + 1];
    const float v2a = hv2[(size_t)row * 2],     v2b = hv2[(size_t)row * 2 + 1];
    const int   i1a = hi1[(size_t)row * 2],     i1b = hi1[(size_t)row * 2 + 1];
    float v1, v2; int i1;
    if (v1b > v1a) { v1 = v1b; i1 = i1b; v2 = fmaxf(v1a, v2b); }
    else           { v1 = v1a; i1 = i1a; v2 = fmaxf(v2a, v1b); }
    bestk[row] = i1;
    if (v1 - v2 < GAP_T) {
        const int pos = atomicAdd(rcnt, 1);
        rlist[pos] = row;
    }
}

// ---------------------------------------------------------------------------
// Kernel D: exact f32 rescue over the compacted row list; fixes bestk only.
// ---------------------------------------------------------------------------
__global__ __launch_bounds__(256)
void vq_rescue(const float* __restrict__ z, const float* __restrict__ cff,
               const int* __restrict__ rlist, const int* __restrict__ rcnt,
               int* __restrict__ bestk) {
    const int cnt = rcnt[0];
    const int tid = threadIdx.x;
    const int l   = tid & 63;
    const int wv  = tid >> 6;        // 0..3
    __shared__ float zs[D];
    __shared__ float wvv[4];
    __shared__ int   wvi[4];

    for (int i = blockIdx.x; i < cnt; i += gridDim.x) {
        const int row = rlist[i];
        __syncthreads();             // protect zs/wvv reuse across iterations
        reinterpret_cast<float4*>(zs)[tid] =
            reinterpret_cast<const float4*>(z + (size_t)row * D)[tid];
        __syncthreads();

        float v1 = -INFINITY;
        int   i1 = 0;
#pragma unroll 4
        for (int kk = 0; kk < 128; ++kk) {
            const int k = wv * 128 + kk;
            const float4* cr = reinterpret_cast<const float4*>(cff + (size_t)k * D);
            float s = 0.f;
#pragma unroll
            for (int j = 0; j < 4; ++j) {
                const float4 c = cr[j * 64 + l];           // coalesced 1KB/wave
                const float4 a = *reinterpret_cast<const float4*>(zs + j * 256 + l * 4);
                s = fmaf(c.x, a.x, s); s = fmaf(c.y, a.y, s);
                s = fmaf(c.z, a.z, s); s = fmaf(c.w, a.w, s);
            }
#pragma unroll
            for (int off = 32; off > 0; off >>= 1) s += __shfl_xor(s, off);
            if (s > v1) { v1 = s; i1 = k; }   // ascending k: first-index ties
        }
        if (l == 0) { wvv[wv] = v1; wvi[wv] = i1; }
        __syncthreads();
        if (tid == 0) {
            float bv = wvv[0]; int bi = wvi[0];
            for (int w = 1; w < 4; ++w)
                if (wvv[w] > bv || (wvv[w] == bv && wvi[w] < bi)) { bv = wvv[w]; bi = wvi[w]; }
            bestk[row] = bi;
        }
    }
}

// ---------------------------------------------------------------------------
// Kernel E: streaming epilogue. out = target * (1 + E[bestk[row]]).
// ---------------------------------------------------------------------------
__global__ __launch_bounds__(256)
void vq_epilogue(const float* __restrict__ tgt, const float* __restrict__ E,
                 const int* __restrict__ bestk, float* __restrict__ out) {
    const int tid = threadIdx.x;
    const int r0  = blockIdx.x * 8;
    int bi[8];
#pragma unroll
    for (int r = 0; r < 8; ++r) bi[r] = bestk[r0 + r];
#pragma unroll
    for (int r = 0; r < 8; ++r) {
        const float4 tv = reinterpret_cast<const float4*>(tgt + (size_t)(r0 + r) * D)[tid];
        const float4 ev = reinterpret_cast<const float4*>(E + (size_t)bi[r] * D)[tid];
        float4 o;
        o.x = tv.x * (1.0f + ev.x);
        o.y = tv.y * (1.0f + ev.y);
        o.z = tv.z * (1.0f + ev.z);
        o.w = tv.w * (1.0f + ev.w);
        reinterpret_cast<float4*>(out + (size_t)(r0 + r) * D)[tid] = o;
    }
}

extern "C" void kernel_launch(void* const* d_in, const int* in_sizes, int n_in,
                              void* d_out, int out_size, void* d_ws, size_t ws_size,
                              hipStream_t stream) {
    const float* z        = (const float*)d_in[0];
    const float* target   = (const float*)d_in[1];
    const float* codebook = (const float*)d_in[2];
    const float* E        = (const float*)d_in[3];
    float* out = (float*)d_out;

    unsigned short* cbp   = (unsigned short*)d_ws;              // 2 MB packed hi/lo
    float*          cff   = (float*)(cbp + (size_t)K * D * 2);  // 2 MB f32
    int*            bestk = (int*)(cff + (size_t)K * D);        // 64 KB
    int*            rlist = bestk + ROWS;                       // 64 KB
    int*            rcnt  = rlist + ROWS;                       // 4 B (+pad)
    float*          hv1   = (float*)(rcnt + 64);                // 128 KB
    float*          hv2   = hv1 + (size_t)ROWS * 2;             // 128 KB
    int*            hi1   = (int*)(hv2 + (size_t)ROWS * 2);     // 128 KB

    const int rows = in_sizes[0] / D;                           // 16384
    hipLaunchKernelGGL(prep_codebook, dim3(K), dim3(256), 0, stream,
                       codebook, cbp, cff, rcnt);
    hipLaunchKernelGGL(vq_topk, dim3((rows / BM) * 2), dim3(512), 0, stream,
                       z, cbp, hv1, hv2, hi1);
    hipLaunchKernelGGL(vq_merge, dim3(rows / 256), dim3(256), 0, stream,
                       hv1, hv2, hi1, bestk, rlist, rcnt);
    hipLaunchKernelGGL(vq_rescue, dim3(256), dim3(256), 0, stream,
                       z, cff, rlist, rcnt, bestk);
    hipLaunchKernelGGL(vq_epilogue, dim3(rows / 8), dim3(256), 0, stream,
                       target, E, bestk, out);
}

// Round 10
// 165.550 us; speedup vs baseline: 1.5261x; 1.5261x over previous
//
#include <hip/hip_runtime.h>
#include <math.h>

typedef short  short8  __attribute__((ext_vector_type(8)));
typedef short  short4v __attribute__((ext_vector_type(4)));
typedef float  f32x4   __attribute__((ext_vector_type(4)));

constexpr int D   = 1024;   // d_in = d_g
constexpr int K   = 512;    // codebook size
constexpr int BM  = 64;     // rows per block (vq_topk)
constexpr int KP  = 256;    // k-panel (f32 elements)
constexpr int ROWS = 16384;
constexpr float GAP_T = 2e-3f;   // ~400 sigma of 3-term split-bf16 noise

__device__ __forceinline__ unsigned short f2bf(float f) {
    unsigned u = __float_as_uint(f);
    u += 0x7FFFu + ((u >> 16) & 1u);          // round-to-nearest-even
    return (unsigned short)(u >> 16);
}
__device__ __forceinline__ float bf2f(unsigned short h) {
    return __uint_as_float(((unsigned)h) << 16);
}
// convert one float4 -> bf16 hi/lo 8B chunks and store to LDS
__device__ __forceinline__ void cvt_write(const float4 v,
                                          unsigned char* dh, unsigned char* dl) {
    const unsigned short h0 = f2bf(v.x), h1 = f2bf(v.y), h2 = f2bf(v.z), h3 = f2bf(v.w);
    const short4v hv = { (short)h0, (short)h1, (short)h2, (short)h3 };
    const short4v lv = { (short)f2bf(v.x - bf2f(h0)), (short)f2bf(v.y - bf2f(h1)),
                         (short)f2bf(v.z - bf2f(h2)), (short)f2bf(v.w - bf2f(h3)) };
    *reinterpret_cast<short4v*>(dh) = hv;
    *reinterpret_cast<short4v*>(dl) = lv;
}

// ---------------------------------------------------------------------------
// Kernel A: normalize codebook rows; emit MFMA-fragment-packed bf16 hi/lo
// (cbp) + f32 copy (cff, for rescue). Also zeroes the rescue counter.
// ---------------------------------------------------------------------------
__global__ __launch_bounds__(256)
void prep_codebook(const float* __restrict__ cb, unsigned short* __restrict__ cbp,
                   float* __restrict__ cff, int* __restrict__ rcnt) {
    if (blockIdx.x == 0 && threadIdx.x == 0) rcnt[0] = 0;
    const int n = blockIdx.x, tid = threadIdx.x;
    const float4 v = reinterpret_cast<const float4*>(cb + (size_t)n * D)[tid];
    float ss = v.x*v.x + v.y*v.y + v.z*v.z + v.w*v.w;
#pragma unroll
    for (int off = 32; off > 0; off >>= 1) ss += __shfl_down(ss, off);
    __shared__ float wss[4];
    if ((tid & 63) == 0) wss[tid >> 6] = ss;
    __syncthreads();
    const float tot   = wss[0] + wss[1] + wss[2] + wss[3];
    const float scale = 1.0f / fmaxf(sqrtf(tot), 1e-12f);
    float f[4] = { v.x*scale, v.y*scale, v.z*scale, v.w*scale };
    float4 fv = { f[0], f[1], f[2], f[3] };
    reinterpret_cast<float4*>(cff + (size_t)n * D)[tid] = fv;

    unsigned short h[4], lo[4];
#pragma unroll
    for (int i = 0; i < 4; ++i) { h[i] = f2bf(f[i]); lo[i] = f2bf(f[i] - bf2f(h[i])); }
    short4v hv = { (short)h[0], (short)h[1], (short)h[2], (short)h[3] };
    short4v lv = { (short)lo[0], (short)lo[1], (short)lo[2], (short)lo[3] };

    const int nt_g = n >> 4;           // code tile 0..31
    const int lr   = n & 15;
    const int ks_g = tid >> 3;         // k-step 0..31
    const int lg   = (tid >> 1) & 3;
    const int half = tid & 1;
    const size_t fbase = ((size_t)(nt_g * 32 + ks_g) * 2) * 1024;   // bytes
    unsigned char* base = (unsigned char*)cbp;
    *reinterpret_cast<short4v*>(base + fbase + (lg * 16 + lr) * 16 + half * 8) = hv;
    *reinterpret_cast<short4v*>(base + fbase + 1024 + (lg * 16 + lr) * 16 + half * 8) = lv;
}

// ---------------------------------------------------------------------------
// Kernel B: 3-product split-bf16 MFMA GEMM + top-2 -> bestk + rescue list.
// BM=64 rows x all 512 codes per block, grid 256 (1 block/CU), 8 waves.
// Double-buffered LDS panels (2 x (32K hi + 32K lo) = 128 KB): per panel ONE
// barrier; inside the MFMA phase we (a) issue next panel's global loads
// early, (b) run 8 k-steps x 48 MFMA with B reg-dbuf, (c) convert+write the
// next panel into the other LDS buffer. Staging fully overlaps MFMA.
// ---------------------------------------------------------------------------
__global__ __launch_bounds__(512, 1)
void vq_topk(const float* __restrict__ z,
             const unsigned short* __restrict__ cbp,
             int* __restrict__ bestk, int* __restrict__ rlist,
             int* __restrict__ rcnt) {
    __shared__ alignas(16) unsigned char LDS[2][BM * KP * 2 * 2];  // 2 x 64 KB

    const int tid = threadIdx.x;
    const int r0  = blockIdx.x * BM;
    const int l   = tid & 63;
    const int wv  = tid >> 6;        // 0..7
    const int lr  = l & 15;
    const int lg  = l >> 4;

    f32x4 acc[4][4];
#pragma unroll
    for (int m = 0; m < 4; ++m)
#pragma unroll
        for (int nt = 0; nt < 4; ++nt) acc[m][nt] = (f32x4){0.f, 0.f, 0.f, 0.f};

    const int aswz = (lr & 7) << 4;
    const short8* bp = reinterpret_cast<const short8*>(cbp) + l;

    // staging decomposition: wave wv covers rows wv+8c (c=0..7) at f4-col l
    const int c4    = l;
    const int row0  = wv;
    const int swz_w = (row0 & 7) << 4;   // (row0+8c)&7 == row0&7
    const float* zbase = z + (size_t)(r0 + row0) * D + c4 * 4;

    // prologue: panel 0 -> buf 0
    {
        float4 zn[8];
#pragma unroll
        for (int c = 0; c < 8; ++c)
            zn[c] = *reinterpret_cast<const float4*>(zbase + (size_t)(8 * c) * D);
#pragma unroll
        for (int c = 0; c < 8; ++c) {
            const int ad = ((row0 + 8 * c) * 512 + c4 * 8) ^ swz_w;
            cvt_write(zn[c], &LDS[0][ad], &LDS[0][32768 + ad]);
        }
    }

    for (int p = 0; p < 4; ++p) {
        __syncthreads();                      // buf[p&1] staged; buf[(p+1)&1] free
        unsigned char* Ah  = &LDS[p & 1][0];
        unsigned char* Al  = Ah + 32768;
        unsigned char* Ahn = &LDS[(p + 1) & 1][0];

        // (a) issue next panel's global loads early (T14)
        float4 zn[8];
        if (p < 3) {
#pragma unroll
            for (int c = 0; c < 8; ++c)
                zn[c] = *reinterpret_cast<const float4*>(
                    zbase + (size_t)(8 * c) * D + (p + 1) * KP);
        }

        // (b) MFMA: 8 k-steps of 32; B reg-dbuf one step ahead
        short8 bb[2][4][2];
#pragma unroll
        for (int nt = 0; nt < 4; ++nt) {
            const size_t fi = ((size_t)((wv * 4 + nt) * 32 + p * 8) * 2);
            bb[0][nt][0] = bp[(fi + 0) * 64];
            bb[0][nt][1] = bp[(fi + 1) * 64];
        }
#pragma unroll
        for (int ks = 0; ks < 8; ++ks) {
            const int cur = ks & 1, nxt = cur ^ 1;
            if (ks < 7) {
#pragma unroll
                for (int nt = 0; nt < 4; ++nt) {
                    const size_t fi = ((size_t)((wv * 4 + nt) * 32 + p * 8 + ks + 1) * 2);
                    bb[nxt][nt][0] = bp[(fi + 0) * 64];
                    bb[nxt][nt][1] = bp[(fi + 1) * 64];
                }
            }
            short8 ah[4], al[4];
#pragma unroll
            for (int m = 0; m < 4; ++m) {
                const int ad = ((m * 16 + lr) * 512 + lg * 16 + ks * 64) ^ aswz;
                ah[m] = *reinterpret_cast<const short8*>(Ah + ad);
                al[m] = *reinterpret_cast<const short8*>(Al + ad);
            }
#pragma unroll
            for (int nt = 0; nt < 4; ++nt) {
                const short8 bh = bb[cur][nt][0];
                const short8 bl = bb[cur][nt][1];
#pragma unroll
                for (int m = 0; m < 4; ++m) {
                    acc[m][nt] = __builtin_amdgcn_mfma_f32_16x16x32_bf16(ah[m], bh, acc[m][nt], 0, 0, 0);
                    acc[m][nt] = __builtin_amdgcn_mfma_f32_16x16x32_bf16(ah[m], bl, acc[m][nt], 0, 0, 0);
                    acc[m][nt] = __builtin_amdgcn_mfma_f32_16x16x32_bf16(al[m], bh, acc[m][nt], 0, 0, 0);
                }
            }
        }

        // (c) convert + write next panel into the other buffer (VALU tail)
        if (p < 3) {
#pragma unroll
            for (int c = 0; c < 8; ++c) {
                const int ad = ((row0 + 8 * c) * 512 + c4 * 8) ^ swz_w;
                cvt_write(zn[c], Ahn + ad, Ahn + 32768 + ad);
            }
        }
    }

    // ---- LDS no longer needed for A: alias reduction arrays ----
    __syncthreads();
    float* cv1 = (float*)&LDS[0][0];          // [8][BM]
    float* cv2 = (float*)&LDS[0][4096];       // [8][BM]
    int*   ci1 = (int*)  &LDS[0][8192];       // [8][BM]

    // ---- top-2 per row: nt scan, 16-lane butterfly, wave merge ----
    // acc[m][nt][r] = logits[row = m*16 + lg*4 + r][code = wv*64 + nt*16 + lr]
#pragma unroll
    for (int m = 0; m < 4; ++m)
#pragma unroll
        for (int r = 0; r < 4; ++r) {
            float v1 = acc[m][0][r];
            int   i1 = wv * 64 + lr;
            float v2 = -INFINITY;
#pragma unroll
            for (int nt = 1; nt < 4; ++nt) {
                const float v = acc[m][nt][r];
                const int   n = wv * 64 + nt * 16 + lr;
                if (v > v1) { v2 = v1; v1 = v; i1 = n; }
                else        { v2 = fmaxf(v2, v); }
            }
#pragma unroll
            for (int msk = 1; msk < 16; msk <<= 1) {
                const float ov1 = __shfl_xor(v1, msk);
                const float ov2 = __shfl_xor(v2, msk);
                const int   oi1 = __shfl_xor(i1, msk);
                if (ov1 > v1 || (ov1 == v1 && oi1 < i1)) { v2 = fmaxf(v1, ov2); v1 = ov1; i1 = oi1; }
                else                                     { v2 = fmaxf(v2, ov1); }
            }
            if (lr == 0) {
                const int row = m * 16 + lg * 4 + r;
                cv1[wv * BM + row] = v1; cv2[wv * BM + row] = v2; ci1[wv * BM + row] = i1;
            }
        }
    __syncthreads();
    if (tid < BM) {
        float v1 = cv1[tid], v2 = cv2[tid];
        int   i1 = ci1[tid];
        for (int w = 1; w < 8; ++w) {
            const float a1 = cv1[w * BM + tid], a2 = cv2[w * BM + tid];
            const int   b1 = ci1[w * BM + tid];
            if (a1 > v1 || (a1 == v1 && b1 < i1)) { v2 = fmaxf(v1, a2); v1 = a1; i1 = b1; }
            else                                  { v2 = fmaxf(v2, a1); }
        }
        bestk[r0 + tid] = i1;
        if (v1 - v2 < GAP_T) {
            const int pos = atomicAdd(rcnt, 1);
            rlist[pos] = r0 + tid;
        }
    }
}

// ---------------------------------------------------------------------------
// Kernel C: exact f32 rescue over the compacted row list; fixes bestk only.
// ---------------------------------------------------------------------------
__global__ __launch_bounds__(256)
void vq_rescue(const float* __restrict__ z, const float* __restrict__ cff,
               const int* __restrict__ rlist, const int* __restrict__ rcnt,
               int* __restrict__ bestk) {
    const int cnt = rcnt[0];
    const int tid = threadIdx.x;
    const int l   = tid & 63;
    const int wv  = tid >> 6;        // 0..3
    __shared__ float zs[D];
    __shared__ float wvv[4];
    __shared__ int   wvi[4];

    for (int i = blockIdx.x; i < cnt; i += gridDim.x) {
        const int row = rlist[i];
        __syncthreads();             // protect zs/wvv reuse across iterations
        reinterpret_cast<float4*>(zs)[tid] =
            reinterpret_cast<const float4*>(z + (size_t)row * D)[tid];
        __syncthreads();

        float v1 = -INFINITY;
        int   i1 = 0;
#pragma unroll 4
        for (int kk = 0; kk < 128; ++kk) {
            const int k = wv * 128 + kk;
            const float4* cr = reinterpret_cast<const float4*>(cff + (size_t)k * D);
            float s = 0.f;
#pragma unroll
            for (int j = 0; j < 4; ++j) {
                const float4 c = cr[j * 64 + l];           // coalesced 1KB/wave
                const float4 a = *reinterpret_cast<const float4*>(zs + j * 256 + l * 4);
                s = fmaf(c.x, a.x, s); s = fmaf(c.y, a.y, s);
                s = fmaf(c.z, a.z, s); s = fmaf(c.w, a.w, s);
            }
#pragma unroll
            for (int off = 32; off > 0; off >>= 1) s += __shfl_xor(s, off);
            if (s > v1) { v1 = s; i1 = k; }   // ascending k: first-index ties
        }
        if (l == 0) { wvv[wv] = v1; wvi[wv] = i1; }
        __syncthreads();
        if (tid == 0) {
            float bv = wvv[0]; int bi = wvi[0];
            for (int w = 1; w < 4; ++w)
                if (wvv[w] > bv || (wvv[w] == bv && wvi[w] < bi)) { bv = wvv[w]; bi = wvi[w]; }
            bestk[row] = bi;
        }
    }
}

// ---------------------------------------------------------------------------
// Kernel D: streaming epilogue. out = target * (1 + E[bestk[row]]).
// ---------------------------------------------------------------------------
__global__ __launch_bounds__(256)
void vq_epilogue(const float* __restrict__ tgt, const float* __restrict__ E,
                 const int* __restrict__ bestk, float* __restrict__ out) {
    const int tid = threadIdx.x;
    const int r0  = blockIdx.x * 8;
    int bi[8];
#pragma unroll
    for (int r = 0; r < 8; ++r) bi[r] = bestk[r0 + r];
#pragma unroll
    for (int r = 0; r < 8; ++r) {
        const float4 tv = reinterpret_cast<const float4*>(tgt + (size_t)(r0 + r) * D)[tid];
        const float4 ev = reinterpret_cast<const float4*>(E + (size_t)bi[r] * D)[tid];
        float4 o;
        o.x = tv.x * (1.0f + ev.x);
        o.y = tv.y * (1.0f + ev.y);
        o.z = tv.z * (1.0f + ev.z);
        o.w = tv.w * (1.0f + ev.w);
        reinterpret_cast<float4*>(out + (size_t)(r0 + r) * D)[tid] = o;
    }
}

extern "C" void kernel_launch(void* const* d_in, const int* in_sizes, int n_in,
                              void* d_out, int out_size, void* d_ws, size_t ws_size,
                              hipStream_t stream) {
    const float* z        = (const float*)d_in[0];
    const float* target   = (const float*)d_in[1];
    const float* codebook = (const float*)d_in[2];
    const float* E        = (const float*)d_in[3];
    float* out = (float*)d_out;

    unsigned short* cbp   = (unsigned short*)d_ws;              // 2 MB packed hi/lo
    float*          cff   = (float*)(cbp + (size_t)K * D * 2);  // 2 MB f32
    int*            bestk = (int*)(cff + (size_t)K * D);        // 64 KB
    int*            rlist = bestk + ROWS;                       // 64 KB
    int*            rcnt  = rlist + ROWS;                       // 4 B

    const int rows = in_sizes[0] / D;                           // 16384
    hipLaunchKernelGGL(prep_codebook, dim3(K), dim3(256), 0, stream,
                       codebook, cbp, cff, rcnt);
    hipLaunchKernelGGL(vq_topk, dim3(rows / BM), dim3(512), 0, stream,
                       z, cbp, bestk, rlist, rcnt);
    hipLaunchKernelGGL(vq_rescue, dim3(256), dim3(256), 0, stream,
                       z, cff, rlist, rcnt, bestk);
    hipLaunchKernelGGL(vq_epilogue, dim3(rows / 8), dim3(256), 0, stream,
                       target, E, bestk, out);
}

// Round 11
// 162.985 us; speedup vs baseline: 1.5501x; 1.0157x over previous
//
#include <hip/hip_runtime.h>
#include <math.h>

typedef short  short8  __attribute__((ext_vector_type(8)));
typedef short  short4v __attribute__((ext_vector_type(4)));
typedef float  f32x4   __attribute__((ext_vector_type(4)));

constexpr int D   = 1024;   // d_in = d_g
constexpr int K   = 512;    // codebook size
constexpr int BM  = 64;     // rows per block (vq_topk)
constexpr int KP  = 256;    // k-panel (f32 elements)
constexpr int ROWS = 16384;
constexpr float GAP_T = 2e-3f;   // ~25 sigma of 3-term split-bf16 noise

__device__ __forceinline__ unsigned short f2bf(float f) {
    unsigned u = __float_as_uint(f);
    u += 0x7FFFu + ((u >> 16) & 1u);          // round-to-nearest-even
    return (unsigned short)(u >> 16);
}
__device__ __forceinline__ float bf2f(unsigned short h) {
    return __uint_as_float(((unsigned)h) << 16);
}
// convert one float4 -> bf16 hi/lo 8B chunks and store to LDS
__device__ __forceinline__ void cvt_write(const float4 v,
                                          unsigned char* dh, unsigned char* dl) {
    const unsigned short h0 = f2bf(v.x), h1 = f2bf(v.y), h2 = f2bf(v.z), h3 = f2bf(v.w);
    const short4v hv = { (short)h0, (short)h1, (short)h2, (short)h3 };
    const short4v lv = { (short)f2bf(v.x - bf2f(h0)), (short)f2bf(v.y - bf2f(h1)),
                         (short)f2bf(v.z - bf2f(h2)), (short)f2bf(v.w - bf2f(h3)) };
    *reinterpret_cast<short4v*>(dh) = hv;
    *reinterpret_cast<short4v*>(dl) = lv;
}

// ---------------------------------------------------------------------------
// Kernel A: normalize codebook rows; emit MFMA-fragment-packed bf16 hi/lo
// (cbp) + f32 copy (cff, for rescue). Also zeroes the rescue counter.
// ---------------------------------------------------------------------------
__global__ __launch_bounds__(256)
void prep_codebook(const float* __restrict__ cb, unsigned short* __restrict__ cbp,
                   float* __restrict__ cff, int* __restrict__ rcnt) {
    if (blockIdx.x == 0 && threadIdx.x == 0) rcnt[0] = 0;
    const int n = blockIdx.x, tid = threadIdx.x;
    const float4 v = reinterpret_cast<const float4*>(cb + (size_t)n * D)[tid];
    float ss = v.x*v.x + v.y*v.y + v.z*v.z + v.w*v.w;
#pragma unroll
    for (int off = 32; off > 0; off >>= 1) ss += __shfl_down(ss, off);
    __shared__ float wss[4];
    if ((tid & 63) == 0) wss[tid >> 6] = ss;
    __syncthreads();
    const float tot   = wss[0] + wss[1] + wss[2] + wss[3];
    const float scale = 1.0f / fmaxf(sqrtf(tot), 1e-12f);
    float f[4] = { v.x*scale, v.y*scale, v.z*scale, v.w*scale };
    float4 fv = { f[0], f[1], f[2], f[3] };
    reinterpret_cast<float4*>(cff + (size_t)n * D)[tid] = fv;

    unsigned short h[4], lo[4];
#pragma unroll
    for (int i = 0; i < 4; ++i) { h[i] = f2bf(f[i]); lo[i] = f2bf(f[i] - bf2f(h[i])); }
    short4v hv = { (short)h[0], (short)h[1], (short)h[2], (short)h[3] };
    short4v lv = { (short)lo[0], (short)lo[1], (short)lo[2], (short)lo[3] };

    const int nt_g = n >> 4;           // code tile 0..31
    const int lr   = n & 15;
    const int ks_g = tid >> 3;         // k-step 0..31
    const int lg   = (tid >> 1) & 3;
    const int half = tid & 1;
    const size_t fbase = ((size_t)(nt_g * 32 + ks_g) * 2) * 1024;   // bytes
    unsigned char* base = (unsigned char*)cbp;
    *reinterpret_cast<short4v*>(base + fbase + (lg * 16 + lr) * 16 + half * 8) = hv;
    *reinterpret_cast<short4v*>(base + fbase + 1024 + (lg * 16 + lr) * 16 + half * 8) = lv;
}

// ---------------------------------------------------------------------------
// Kernel B: 3-product split-bf16 MFMA GEMM + top-2 -> bestk + rescue list.
// BM=64 rows x all 512 codes per block, grid 256, 8 waves (2/SIMD).
// amdgpu_waves_per_eu(2,2): tell the register allocator the TRUE occupancy
// (LDS caps us at 2 waves/SIMD) so the B-prefetch pipeline survives in regs
// (default heuristic squeezed to 116 VGPR and sank all prefetches -> 77us
// latency-bound plateau across r7/r8/r10).
// ---------------------------------------------------------------------------
__attribute__((amdgpu_waves_per_eu(2, 2)))
__global__ __launch_bounds__(512)
void vq_topk(const float* __restrict__ z,
             const unsigned short* __restrict__ cbp,
             int* __restrict__ bestk, int* __restrict__ rlist,
             int* __restrict__ rcnt) {
    __shared__ alignas(16) unsigned char LDS[2][BM * KP * 2 * 2];  // 2 x 64 KB

    const int tid = threadIdx.x;
    const int r0  = blockIdx.x * BM;
    const int l   = tid & 63;
    const int wv  = tid >> 6;        // 0..7
    const int lr  = l & 15;
    const int lg  = l >> 4;

    f32x4 acc[4][4];
#pragma unroll
    for (int m = 0; m < 4; ++m)
#pragma unroll
        for (int nt = 0; nt < 4; ++nt) acc[m][nt] = (f32x4){0.f, 0.f, 0.f, 0.f};

    const int aswz = (lr & 7) << 4;
    // lane-resolved base into packed B; fragment fi lives at byte fi*1024
    const unsigned char* bbase = (const unsigned char*)cbp + l * 16;
#define BFRAG(fi) (*reinterpret_cast<const short8*>(bbase + (unsigned)(fi) * 1024u))

    // staging decomposition: wave wv covers rows wv+8c (c=0..7) at f4-col l
    const int c4    = l;
    const int row0  = wv;
    const int swz_w = (row0 & 7) << 4;   // (row0+8c)&7 == row0&7
    const float* zbase = z + (size_t)(r0 + row0) * D + c4 * 4;

    // prologue: panel 0 -> buf 0
    {
        float4 zn[8];
#pragma unroll
        for (int c = 0; c < 8; ++c)
            zn[c] = *reinterpret_cast<const float4*>(zbase + (size_t)(8 * c) * D);
#pragma unroll
        for (int c = 0; c < 8; ++c) {
            const int ad = ((row0 + 8 * c) * 512 + c4 * 8) ^ swz_w;
            cvt_write(zn[c], &LDS[0][ad], &LDS[0][32768 + ad]);
        }
    }

#pragma unroll 1
    for (int p = 0; p < 4; ++p) {
        __syncthreads();                      // buf[p&1] staged; buf[(p+1)&1] free
        unsigned char* Ah  = &LDS[p & 1][0];
        unsigned char* Al  = Ah + 32768;
        unsigned char* Ahn = &LDS[(p + 1) & 1][0];

        // (a) issue next panel's global z loads early (T14)
        float4 zn[8];
        if (p < 3) {
#pragma unroll
            for (int c = 0; c < 8; ++c)
                zn[c] = *reinterpret_cast<const float4*>(
                    zbase + (size_t)(8 * c) * D + (p + 1) * KP);
        }

        // (b) MFMA: 8 k-steps of 32; B register pipeline one step ahead
        const int fp0 = (wv * 4 * 32 + p * 8) * 2;   // fragment index base
        short8 b0[4][2], b1[4][2];
#pragma unroll
        for (int nt = 0; nt < 4; ++nt) {
            const int fi = fp0 + nt * 64;            // (wv*4+nt)*32*2 = nt*64
            b0[nt][0] = BFRAG(fi + 0);
            b0[nt][1] = BFRAG(fi + 1);
        }
#pragma unroll 2
        for (int ks = 0; ks < 8; ++ks) {
            if (ks < 7) {
#pragma unroll
                for (int nt = 0; nt < 4; ++nt) {
                    const int fi = fp0 + nt * 64 + (ks + 1) * 2;
                    b1[nt][0] = BFRAG(fi + 0);
                    b1[nt][1] = BFRAG(fi + 1);
                }
            }
            short8 ah[4], al[4];
#pragma unroll
            for (int m = 0; m < 4; ++m) {
                const int ad = ((m * 16 + lr) * 512 + lg * 16 + ks * 64) ^ aswz;
                ah[m] = *reinterpret_cast<const short8*>(Ah + ad);
                al[m] = *reinterpret_cast<const short8*>(Al + ad);
            }
#pragma unroll
            for (int nt = 0; nt < 4; ++nt) {
                const short8 bh = b0[nt][0];
                const short8 bl = b0[nt][1];
#pragma unroll
                for (int m = 0; m < 4; ++m) {
                    acc[m][nt] = __builtin_amdgcn_mfma_f32_16x16x32_bf16(ah[m], bh, acc[m][nt], 0, 0, 0);
                    acc[m][nt] = __builtin_amdgcn_mfma_f32_16x16x32_bf16(ah[m], bl, acc[m][nt], 0, 0, 0);
                    acc[m][nt] = __builtin_amdgcn_mfma_f32_16x16x32_bf16(al[m], bh, acc[m][nt], 0, 0, 0);
                }
            }
            // rotate pipeline regs (renamed away by unroll-2)
#pragma unroll
            for (int nt = 0; nt < 4; ++nt) {
                b0[nt][0] = b1[nt][0];
                b0[nt][1] = b1[nt][1];
            }
        }

        // (c) convert + write next panel into the other buffer (VALU tail)
        if (p < 3) {
#pragma unroll
            for (int c = 0; c < 8; ++c) {
                const int ad = ((row0 + 8 * c) * 512 + c4 * 8) ^ swz_w;
                cvt_write(zn[c], Ahn + ad, Ahn + 32768 + ad);
            }
        }
    }
#undef BFRAG

    // ---- LDS no longer needed for A: alias reduction arrays ----
    __syncthreads();
    float* cv1 = (float*)&LDS[0][0];          // [8][BM]
    float* cv2 = (float*)&LDS[0][4096];       // [8][BM]
    int*   ci1 = (int*)  &LDS[0][8192];       // [8][BM]

    // ---- top-2 per row: nt scan, 16-lane butterfly, wave merge ----
    // acc[m][nt][r] = logits[row = m*16 + lg*4 + r][code = wv*64 + nt*16 + lr]
#pragma unroll
    for (int m = 0; m < 4; ++m)
#pragma unroll
        for (int r = 0; r < 4; ++r) {
            float v1 = acc[m][0][r];
            int   i1 = wv * 64 + lr;
            float v2 = -INFINITY;
#pragma unroll
            for (int nt = 1; nt < 4; ++nt) {
                const float v = acc[m][nt][r];
                const int   n = wv * 64 + nt * 16 + lr;
                if (v > v1) { v2 = v1; v1 = v; i1 = n; }
                else        { v2 = fmaxf(v2, v); }
            }
#pragma unroll
            for (int msk = 1; msk < 16; msk <<= 1) {
                const float ov1 = __shfl_xor(v1, msk);
                const float ov2 = __shfl_xor(v2, msk);
                const int   oi1 = __shfl_xor(i1, msk);
                if (ov1 > v1 || (ov1 == v1 && oi1 < i1)) { v2 = fmaxf(v1, ov2); v1 = ov1; i1 = oi1; }
                else                                     { v2 = fmaxf(v2, ov1); }
            }
            if (lr == 0) {
                const int row = m * 16 + lg * 4 + r;
                cv1[wv * BM + row] = v1; cv2[wv * BM + row] = v2; ci1[wv * BM + row] = i1;
            }
        }
    __syncthreads();
    if (tid < BM) {
        float v1 = cv1[tid], v2 = cv2[tid];
        int   i1 = ci1[tid];
        for (int w = 1; w < 8; ++w) {
            const float a1 = cv1[w * BM + tid], a2 = cv2[w * BM + tid];
            const int   b1 = ci1[w * BM + tid];
            if (a1 > v1 || (a1 == v1 && b1 < i1)) { v2 = fmaxf(v1, a2); v1 = a1; i1 = b1; }
            else                                  { v2 = fmaxf(v2, a1); }
        }
        bestk[r0 + tid] = i1;
        if (v1 - v2 < GAP_T) {
            const int pos = atomicAdd(rcnt, 1);
            rlist[pos] = r0 + tid;
        }
    }
}

// ---------------------------------------------------------------------------
// Kernel C: exact f32 rescue over the compacted row list; fixes bestk only.
// ---------------------------------------------------------------------------
__global__ __launch_bounds__(256)
void vq_rescue(const float* __restrict__ z, const float* __restrict__ cff,
               const int* __restrict__ rlist, const int* __restrict__ rcnt,
               int* __restrict__ bestk) {
    const int cnt = rcnt[0];
    const int tid = threadIdx.x;
    const int l   = tid & 63;
    const int wv  = tid >> 6;        // 0..3
    __shared__ float zs[D];
    __shared__ float wvv[4];
    __shared__ int   wvi[4];

    for (int i = blockIdx.x; i < cnt; i += gridDim.x) {
        const int row = rlist[i];
        __syncthreads();             // protect zs/wvv reuse across iterations
        reinterpret_cast<float4*>(zs)[tid] =
            reinterpret_cast<const float4*>(z + (size_t)row * D)[tid];
        __syncthreads();

        float v1 = -INFINITY;
        int   i1 = 0;
#pragma unroll 4
        for (int kk = 0; kk < 128; ++kk) {
            const int k = wv * 128 + kk;
            const float4* cr = reinterpret_cast<const float4*>(cff + (size_t)k * D);
            float s = 0.f;
#pragma unroll
            for (int j = 0; j < 4; ++j) {
                const float4 c = cr[j * 64 + l];           // coalesced 1KB/wave
                const float4 a = *reinterpret_cast<const float4*>(zs + j * 256 + l * 4);
                s = fmaf(c.x, a.x, s); s = fmaf(c.y, a.y, s);
                s = fmaf(c.z, a.z, s); s = fmaf(c.w, a.w, s);
            }
#pragma unroll
            for (int off = 32; off > 0; off >>= 1) s += __shfl_xor(s, off);
            if (s > v1) { v1 = s; i1 = k; }   // ascending k: first-index ties
        }
        if (l == 0) { wvv[wv] = v1; wvi[wv] = i1; }
        __syncthreads();
        if (tid == 0) {
            float bv = wvv[0]; int bi = wvi[0];
            for (int w = 1; w < 4; ++w)
                if (wvv[w] > bv || (wvv[w] == bv && wvi[w] < bi)) { bv = wvv[w]; bi = wvi[w]; }
            bestk[row] = bi;
        }
    }
}

// ---------------------------------------------------------------------------
// Kernel D: streaming epilogue. out = target * (1 + E[bestk[row]]).
// ---------------------------------------------------------------------------
__global__ __launch_bounds__(256)
void vq_epilogue(const float* __restrict__ tgt, const float* __restrict__ E,
                 const int* __restrict__ bestk, float* __restrict__ out) {
    const int tid = threadIdx.x;
    const int r0  = blockIdx.x * 8;
    int bi[8];
#pragma unroll
    for (int r = 0; r < 8; ++r) bi[r] = bestk[r0 + r];
#pragma unroll
    for (int r = 0; r < 8; ++r) {
        const float4 tv = reinterpret_cast<const float4*>(tgt + (size_t)(r0 + r) * D)[tid];
        const float4 ev = reinterpret_cast<const float4*>(E + (size_t)bi[r] * D)[tid];
        float4 o;
        o.x = tv.x * (1.0f + ev.x);
        o.y = tv.y * (1.0f + ev.y);
        o.z = tv.z * (1.0f + ev.z);
        o.w = tv.w * (1.0f + ev.w);
        reinterpret_cast<float4*>(out + (size_t)(r0 + r) * D)[tid] = o;
    }
}

extern "C" void kernel_launch(void* const* d_in, const int* in_sizes, int n_in,
                              void* d_out, int out_size, void* d_ws, size_t ws_size,
                              hipStream_t stream) {
    const float* z        = (const float*)d_in[0];
    const float* target   = (const float*)d_in[1];
    const float* codebook = (const float*)d_in[2];
    const float* E        = (const float*)d_in[3];
    float* out = (float*)d_out;

    unsigned short* cbp   = (unsigned short*)d_ws;              // 2 MB packed hi/lo
    float*          cff   = (float*)(cbp + (size_t)K * D * 2);  // 2 MB f32
    int*            bestk = (int*)(cff + (size_t)K * D);        // 64 KB
    int*            rlist = bestk + ROWS;                       // 64 KB
    int*            rcnt  = rlist + ROWS;                       // 4 B

    const int rows = in_sizes[0] / D;                           // 16384
    hipLaunchKernelGGL(prep_codebook, dim3(K), dim3(256), 0, stream,
                       codebook, cbp, cff, rcnt);
    hipLaunchKernelGGL(vq_topk, dim3(rows / BM), dim3(512), 0, stream,
                       z, cbp, bestk, rlist, rcnt);
    hipLaunchKernelGGL(vq_rescue, dim3(256), dim3(256), 0, stream,
                       z, cff, rlist, rcnt, bestk);
    hipLaunchKernelGGL(vq_epilogue, dim3(rows / 8), dim3(256), 0, stream,
                       target, E, bestk, out);
}